// Round 12
// baseline (279.380 us; speedup 1.0000x reference)
//
#include <hip/hip_runtime.h>
#include <hip/hip_bf16.h>

#define B_ 2048
#define L_ 200
#define D_ 256
#define K_ 8

typedef __attribute__((ext_vector_type(8))) _Float16 half8;
typedef __attribute__((ext_vector_type(4))) _Float16 half4v;
typedef __attribute__((ext_vector_type(4))) float f32x4;

// utT: LTP=240 f16 (480 B rows, 16B-aligned) + 8-f16-group XOR swizzle
// col' = col ^ (((row>>3)&3)<<3)  (R11 layout, current best).
#define LTP 240   // ut_T row stride
#define WP  232   // wH/wL row stride
#define CP  264   // cH/cL/Xs row stride

// LDS offsets (bytes), 16B-aligned.  Total > 81920 pins 1 block/CU
// (=> 128-reg class incl AGPRs; zf/au park in AGPRs -- no spill).
#define OFF_UTT  0                       // ut_T [256][240] f16 = 122880
#define OFF_WH   122880                  // wH   [16][232]  f16 = 7424
#define OFF_WL   130304                  // wL   [16][232]  f16 = 7424
#define OFF_XA   137728                  // XsA  [16][264]  f16 = 8448  (overlay cH)
#define OFF_XB   146176                  // XsB  [16][264]  f16 = 8448  (overlay cL)
#define OFF_LB   154624                  // lb   [8][200]   f32 = 6400
#define OFF_RED  161024                  // red2 [16][8]    f32 = 512
#define LDS_TOTAL 161536                 // < 163840

// ------------------------------------------------------------------
// Fused kernel: 1024 thr (16 waves) per batch.  R11 body; W frags now
// converted fp32->fp16 in-register from W directly (kernel 0 removed).
// ------------------------------------------------------------------
__global__ __launch_bounds__(1024, 4) void fused_mie8(
        const float* __restrict__ X, const float* __restrict__ b_init,
        const int* __restrict__ mask, const float* __restrict__ W,
        float* __restrict__ out) {
    extern __shared__ char dyn[];
    _Float16* utT = (_Float16*)(dyn + OFF_UTT);
    _Float16* wHs = (_Float16*)(dyn + OFF_WH);
    _Float16* wLs = (_Float16*)(dyn + OFF_WL);
    _Float16* XsA = (_Float16*)(dyn + OFF_XA);
    _Float16* XsB = (_Float16*)(dyn + OFF_XB);
    _Float16* cHs = (_Float16*)(dyn + OFF_XA);   // routing overlay
    _Float16* cLs = (_Float16*)(dyn + OFF_XB);   // routing overlay
    float* lb   = (float*)(dyn + OFF_LB);
    float* red2 = (float*)(dyn + OFF_RED);

    const int b = blockIdx.x;
    const int t = threadIdx.x;
    const int w = t >> 6, lane = t & 63;
    const int fr = lane & 15, hi = lane >> 4;

    // ---------- one-time init ----------
    // zero utT physical cols 192..239 for all rows (covers virtual pad
    // cols 208..223 under any swz, plus slack; lt=12 data lands on top).
#pragma unroll
    for (int i = 0; i < 2; ++i) {
        const int n = t + 1024 * i;
        if (n < 1536) {
            const int row = n / 6, q = n - 6 * row;
            *(int4*)&utT[row * LTP + 192 + 8 * q] = make_int4(0, 0, 0, 0);
        }
    }
    // zero wH/wL fully (rows k>=8, cols l>=200 stay zero forever)
    if (t < 928) *(int4*)(dyn + OFF_WH + 16 * t) = make_int4(0, 0, 0, 0);
    // init logits with mask
    for (int idx = t; idx < K_ * L_; idx += 1024) {
        const int k = idx / L_, l = idx - k * L_;
        lb[idx] = (mask[b * L_ + l] == 0) ? -1e9f
                                          : b_init[(size_t)b * (K_ * L_) + idx];
    }

    // hoisted W frags, converted in-register from fp32 W (L2/L3-resident).
    // Same rounding as the old w_to_f16 kernel -> numerics identical.
    half8 bw[8];
    {
        const float* wr = W + (size_t)(16 * w + fr) * 256;
#pragma unroll
        for (int d0 = 0; d0 < 8; ++d0) {
            const float4 a = *(const float4*)(wr + 32 * d0 + 8 * hi);
            const float4 c = *(const float4*)(wr + 32 * d0 + 8 * hi + 4);
            half8 h;
            h[0] = (_Float16)a.x; h[1] = (_Float16)a.y;
            h[2] = (_Float16)a.z; h[3] = (_Float16)a.w;
            h[4] = (_Float16)c.x; h[5] = (_Float16)c.y;
            h[6] = (_Float16)c.z; h[7] = (_Float16)c.w;
            bw[d0] = h;
        }
    }

    // stage X tile 0 (rows 0..15) into XsA
    const float* Xb = X + (size_t)b * L_ * D_;
    const int sc4 = lane * 4;
    {
        const float4 v = *(const float4*)(Xb + w * 256 + sc4);
        half4v h = { (_Float16)v.x, (_Float16)v.y, (_Float16)v.z, (_Float16)v.w };
        *(half4v*)&XsA[w * CP + sc4] = h;
    }
    __syncthreads();

    // ---------- prologue: 13 l-tiles, double-buffered, 1 barrier/tile ----------
    // C-frag write swizzle: rows 16w+4hi+j (j<4) -> swz = (2w + (hi>>1)) & 3
    const int pswz = ((2 * w + (hi >> 1)) & 3) << 3;
    for (int lt = 0; lt < 13; ++lt) {
        _Float16* cur = (lt & 1) ? XsB : XsA;
        _Float16* nxt = (lt & 1) ? XsA : XsB;
        float4 xv = make_float4(0.f, 0.f, 0.f, 0.f);
        if (lt < 12) {
            const int l = 16 * (lt + 1) + w;
            if (l < L_) xv = *(const float4*)(Xb + l * 256 + sc4);
        }
        // u^T tile via swapped MFMA: D[e][l] = sum_d W[e,d] X[l,d]
        f32x4 acc = {};
#pragma unroll
        for (int d0 = 0; d0 < 8; ++d0) {
            const half8 a8 = *(const half8*)&cur[fr * CP + 32 * d0 + 8 * hi];
            acc = __builtin_amdgcn_mfma_f32_16x16x32_f16(bw[d0], a8, acc, 0, 0, 0);
        }
        // write C-frag into swizzled utT: row e=16w+4hi+j, virtual col 16lt+fr
        const int pcol = (16 * lt + fr) ^ pswz;
#pragma unroll
        for (int j = 0; j < 4; ++j)
            utT[(16 * w + 4 * hi + j) * LTP + pcol] = (_Float16)acc[j];
        if (lt < 12) {
            half4v h = { (_Float16)xv.x, (_Float16)xv.y, (_Float16)xv.z, (_Float16)xv.w };
            *(half4v*)&nxt[w * CP + sc4] = h;
        }
        __syncthreads();
    }

    // ---------- one-time register gathers (bw dead; zf/au born) ----------
    // zf: lane(fr,hi) reads virtual cols 32ks+8hi.. of row 16w+fr
    const int zswz = ((2 * w + (fr >> 3)) & 3) << 3;
    half8 zf[7];
#pragma unroll
    for (int ks = 0; ks < 7; ++ks)
        zf[ks] = *(const half8*)&utT[(16 * w + fr) * LTP + ((32 * ks + 8 * hi) ^ zswz)];
    // au: wave w<13, rows 32d0+8hi+j -> swz = hi
    const int aucol = (16 * w + fr) ^ (hi << 3);
    half8 au[8];
    if (w < 13) {
#pragma unroll
        for (int d0 = 0; d0 < 8; ++d0) {
            _Float16 tmp[8];
#pragma unroll
            for (int j = 0; j < 8; ++j)
                tmp[j] = utT[(32 * d0 + 8 * hi + j) * LTP + aucol];
            au[d0] = *(half8*)tmp;
        }
    }

    // ---------- routing iterations ----------
    for (int iter = 0; iter < 3; ++iter) {
        // A. softmax over l (waves 0..7, wave = capsule k); hi/lo fp16 w
        if (t < 512) {
            const int k = t >> 6, ln = t & 63;
            float v[4];
            float m = -1e30f;
#pragma unroll
            for (int i = 0; i < 4; ++i) {
                const int l = ln + 64 * i;
                v[i] = (l < L_) ? lb[k * L_ + l] : -1e30f;
                m = fmaxf(m, v[i]);
            }
#pragma unroll
            for (int off = 32; off >= 1; off >>= 1)
                m = fmaxf(m, __shfl_xor(m, off));
            float e[4], s = 0.f;
#pragma unroll
            for (int i = 0; i < 4; ++i) {
                const int l = ln + 64 * i;
                e[i] = (l < L_) ? __expf(v[i] - m) : 0.f;
                s += e[i];
            }
#pragma unroll
            for (int off = 32; off >= 1; off >>= 1)
                s += __shfl_xor(s, off);
            const float rinv = 1.0f / s;
#pragma unroll
            for (int i = 0; i < 4; ++i) {
                const int l = ln + 64 * i;
                if (l < L_) {
                    const float wv = e[i] * rinv;
                    const _Float16 h = (_Float16)wv;
                    wHs[k * WP + l] = h;
                    wLs[k * WP + l] = (_Float16)(wv - (float)h);
                }
            }
        }
        __syncthreads();

        // B. z-pass MFMA: A = wH/wL (LDS), B = zf (regs); two chains
        f32x4 zH = {}, zL = {};
#pragma unroll
        for (int ks = 0; ks < 7; ++ks) {
            const half8 ah = *(const half8*)&wHs[fr * WP + 32 * ks + 8 * hi];
            const half8 al = *(const half8*)&wLs[fr * WP + 32 * ks + 8 * hi];
            zH = __builtin_amdgcn_mfma_f32_16x16x32_f16(ah, zf[ks], zH, 0, 0, 0);
            zL = __builtin_amdgcn_mfma_f32_16x16x32_f16(al, zf[ks], zL, 0, 0, 0);
        }
        const float z0 = zH[0] + zL[0], z1 = zH[1] + zL[1];
        const float z2 = zH[2] + zL[2], z3 = zH[3] + zL[3];

        // C. norms: reduce z^2 over fr (16-lane groups)
        float sq0 = z0 * z0, sq1 = z1 * z1, sq2 = z2 * z2, sq3 = z3 * z3;
#pragma unroll
        for (int off = 1; off <= 8; off <<= 1) {
            sq0 += __shfl_xor(sq0, off);
            sq1 += __shfl_xor(sq1, off);
            sq2 += __shfl_xor(sq2, off);
            sq3 += __shfl_xor(sq3, off);
        }
        if (fr == 0 && hi < 2) {
            f32x4 sv = { sq0, sq1, sq2, sq3 };
            *(f32x4*)&red2[w * 8 + 4 * hi] = sv;
        }
        __syncthreads();

        // D. squash scale, redundant per wave + shfl broadcast
        float myscale = 0.f;
        if (lane < 8) {
            float ns = 0.f;
#pragma unroll
            for (int ww = 0; ww < 16; ++ww) ns += red2[ww * 8 + lane];
            myscale = ns / ((1.f + ns) * sqrtf(ns + 1e-8f));
        }
        const float sc0 = __shfl(myscale, 4 * hi + 0);
        const float sc1 = __shfl(myscale, 4 * hi + 1);
        const float sc2 = __shfl(myscale, 4 * hi + 2);
        const float sc3 = __shfl(myscale, 4 * hi + 3);

        // E. emit c (hi/lo fp16) or final output
        if (iter == 2) {
            if (hi < 2) {
                float* op = out + (size_t)b * (K_ * D_) + (4 * hi) * D_ + 16 * w + fr;
                op[0 * D_] = sc0 * z0;
                op[1 * D_] = sc1 * z1;
                op[2 * D_] = sc2 * z2;
                op[3 * D_] = sc3 * z3;
            }
        } else {
            if (hi < 2) {
                const float v0 = sc0 * z0, v1 = sc1 * z1;
                const float v2 = sc2 * z2, v3 = sc3 * z3;
                const _Float16 h0 = (_Float16)v0, h1 = (_Float16)v1;
                const _Float16 h2 = (_Float16)v2, h3 = (_Float16)v3;
                const int cb = 16 * w + fr;
                cHs[(4 * hi + 0) * CP + cb] = h0;
                cHs[(4 * hi + 1) * CP + cb] = h1;
                cHs[(4 * hi + 2) * CP + cb] = h2;
                cHs[(4 * hi + 3) * CP + cb] = h3;
                cLs[(4 * hi + 0) * CP + cb] = (_Float16)(v0 - (float)h0);
                cLs[(4 * hi + 1) * CP + cb] = (_Float16)(v1 - (float)h1);
                cLs[(4 * hi + 2) * CP + cb] = (_Float16)(v2 - (float)h2);
                cLs[(4 * hi + 3) * CP + cb] = (_Float16)(v3 - (float)h3);
            }
            __syncthreads();

            // F. b-update MFMA: A = au regs, B = cH/cL LDS (two chains)
            if (w < 13) {
                f32x4 dH = {}, dL = {};
#pragma unroll
                for (int d0 = 0; d0 < 8; ++d0) {
                    const half8 bh = *(const half8*)&cHs[fr * CP + 32 * d0 + 8 * hi];
                    const half8 bl = *(const half8*)&cLs[fr * CP + 32 * d0 + 8 * hi];
                    dH = __builtin_amdgcn_mfma_f32_16x16x32_f16(au[d0], bh, dH, 0, 0, 0);
                    dL = __builtin_amdgcn_mfma_f32_16x16x32_f16(au[d0], bl, dL, 0, 0, 0);
                }
                if (fr < 8) {
#pragma unroll
                    for (int j = 0; j < 4; ++j) {
                        const int l = 16 * w + 4 * hi + j;
                        if (l < L_) lb[fr * L_ + l] += dH[j] + dL[j];
                    }
                }
            }
            __syncthreads();
        }
    }
}

// ==================================================================
extern "C" void kernel_launch(void* const* d_in, const int* in_sizes, int n_in,
                              void* d_out, int out_size, void* d_ws, size_t ws_size,
                              hipStream_t stream) {
    (void)in_sizes; (void)n_in; (void)out_size; (void)d_ws; (void)ws_size;
    const float* behavior = (const float*)d_in[0];   // [B, L, D]
    const float* W        = (const float*)d_in[1];   // [D, D]
    const float* b_init   = (const float*)d_in[2];   // [B, K, L]
    const int*   mask     = (const int*)d_in[3];     // [B, L]
    float* out = (float*)d_out;                      // [B, K, D]

    hipFuncSetAttribute((const void*)fused_mie8,
                        hipFuncAttributeMaxDynamicSharedMemorySize, LDS_TOTAL);

    fused_mie8<<<B_, 1024, LDS_TOTAL, stream>>>(behavior, b_init, mask, W, out);
}

// Round 13
// 257.883 us; speedup vs baseline: 1.0834x; 1.0834x over previous
//
#include <hip/hip_runtime.h>
#include <hip/hip_bf16.h>

#define B_ 2048
#define L_ 200
#define D_ 256
#define K_ 8

typedef __attribute__((ext_vector_type(8))) _Float16 half8;
typedef __attribute__((ext_vector_type(4))) _Float16 half4v;
typedef __attribute__((ext_vector_type(4))) float f32x4;

// utT: LTP=240 f16 (480 B rows, 16B-aligned -> clean b128 reads) plus an
// 8-f16-group XOR swizzle  col' = col ^ (((row>>3)&3)<<3)  which makes the
// transposed au-gather (8-row steps, swz=hi) hit all 32 banks.
// History: 232 = aligned but 8-way conflicted on au-gather (R8);
// 234 = bank-clean but misaligned b128 -> split reads, +22% (R10);
// 240+swizzle = aligned AND bank-clean (R11, best).
#define LTP 240   // ut_T row stride
#define WP  232   // wH/wL row stride (aligned; 2-way conflicts are free)
#define CP  264   // cH/cL/Xs row stride

// LDS offsets (bytes), 16B-aligned.  Total > 81920 pins 1 block/CU
// (=> 128-reg unified class; zf/au park in AGPRs -- no spill; R7/R9
// proved interleaved gathers exceed this budget and spill to scratch).
#define OFF_UTT  0                       // ut_T [256][240] f16 = 122880
#define OFF_WH   122880                  // wH   [16][232]  f16 = 7424
#define OFF_WL   130304                  // wL   [16][232]  f16 = 7424
#define OFF_XA   137728                  // XsA  [16][264]  f16 = 8448  (overlay cH)
#define OFF_XB   146176                  // XsB  [16][264]  f16 = 8448  (overlay cL)
#define OFF_LB   154624                  // lb   [8][200]   f32 = 6400
#define OFF_RED  161024                  // red2 [16][8]    f32 = 512
#define LDS_TOTAL 161536                 // < 163840

// ------------------------------------------------------------------
// Kernel 0: W fp32 -> fp16 (separate tiny kernel; R12 proved folding
// this into the fused kernel costs ~20 us in per-block startup loads)
// ------------------------------------------------------------------
__global__ __launch_bounds__(256) void w_to_f16(const float* __restrict__ W,
                                                _Float16* __restrict__ Wh) {
    const int idx = (blockIdx.x * 256 + threadIdx.x) * 4;
    const float4 v = *(const float4*)(W + idx);
    half4v h = { (_Float16)v.x, (_Float16)v.y, (_Float16)v.z, (_Float16)v.w };
    *(half4v*)(Wh + idx) = h;
}

// ------------------------------------------------------------------
// Fused kernel: 1024 thr (16 waves) per batch.  R8 skeleton, utT
// aligned + XOR-swizzled (R11 layout).  Best measured: 258 us total.
// ------------------------------------------------------------------
__global__ __launch_bounds__(1024, 4) void fused_mie7(
        const float* __restrict__ X, const float* __restrict__ b_init,
        const int* __restrict__ mask, const _Float16* __restrict__ Wh,
        float* __restrict__ out) {
    extern __shared__ char dyn[];
    _Float16* utT = (_Float16*)(dyn + OFF_UTT);
    _Float16* wHs = (_Float16*)(dyn + OFF_WH);
    _Float16* wLs = (_Float16*)(dyn + OFF_WL);
    _Float16* XsA = (_Float16*)(dyn + OFF_XA);
    _Float16* XsB = (_Float16*)(dyn + OFF_XB);
    _Float16* cHs = (_Float16*)(dyn + OFF_XA);   // routing overlay
    _Float16* cLs = (_Float16*)(dyn + OFF_XB);   // routing overlay
    float* lb   = (float*)(dyn + OFF_LB);
    float* red2 = (float*)(dyn + OFF_RED);

    const int b = blockIdx.x;
    const int t = threadIdx.x;
    const int w = t >> 6, lane = t & 63;
    const int fr = lane & 15, hi = lane >> 4;

    // ---------- one-time init ----------
    // zero utT physical cols 192..239 for all rows (covers virtual pad
    // cols 208..223 under any swz, plus slack; lt=12 data lands on top).
#pragma unroll
    for (int i = 0; i < 2; ++i) {
        const int n = t + 1024 * i;
        if (n < 1536) {
            const int row = n / 6, q = n - 6 * row;
            *(int4*)&utT[row * LTP + 192 + 8 * q] = make_int4(0, 0, 0, 0);
        }
    }
    // zero wH/wL fully (rows k>=8, cols l>=200 stay zero forever)
    if (t < 928) *(int4*)(dyn + OFF_WH + 16 * t) = make_int4(0, 0, 0, 0);
    // init logits with mask
    for (int idx = t; idx < K_ * L_; idx += 1024) {
        const int k = idx / L_, l = idx - k * L_;
        lb[idx] = (mask[b * L_ + l] == 0) ? -1e9f
                                          : b_init[(size_t)b * (K_ * L_) + idx];
    }

    // hoisted W frags (MFMA A operand; wave w owns e = 16w..16w+15)
    half8 bw[8];
    {
        const _Float16* wr = Wh + (size_t)(16 * w + fr) * 256;
#pragma unroll
        for (int d0 = 0; d0 < 8; ++d0)
            bw[d0] = *(const half8*)(wr + 32 * d0 + 8 * hi);
    }

    // stage X tile 0 (rows 0..15) into XsA
    const float* Xb = X + (size_t)b * L_ * D_;
    const int sc4 = lane * 4;
    {
        const float4 v = *(const float4*)(Xb + w * 256 + sc4);
        half4v h = { (_Float16)v.x, (_Float16)v.y, (_Float16)v.z, (_Float16)v.w };
        *(half4v*)&XsA[w * CP + sc4] = h;
    }
    __syncthreads();

    // ---------- prologue: 13 l-tiles, double-buffered, 1 barrier/tile ----------
    // C-frag write swizzle: rows 16w+4hi+j (j<4) -> swz = (2w + (hi>>1)) & 3
    const int pswz = ((2 * w + (hi >> 1)) & 3) << 3;
    for (int lt = 0; lt < 13; ++lt) {
        _Float16* cur = (lt & 1) ? XsB : XsA;
        _Float16* nxt = (lt & 1) ? XsA : XsB;
        float4 xv = make_float4(0.f, 0.f, 0.f, 0.f);
        if (lt < 12) {
            const int l = 16 * (lt + 1) + w;
            if (l < L_) xv = *(const float4*)(Xb + l * 256 + sc4);
        }
        // u^T tile via swapped MFMA: D[e][l] = sum_d W[e,d] X[l,d]
        f32x4 acc = {};
#pragma unroll
        for (int d0 = 0; d0 < 8; ++d0) {
            const half8 a8 = *(const half8*)&cur[fr * CP + 32 * d0 + 8 * hi];
            acc = __builtin_amdgcn_mfma_f32_16x16x32_f16(bw[d0], a8, acc, 0, 0, 0);
        }
        // write C-frag into swizzled utT: row e=16w+4hi+j, virtual col 16lt+fr
        const int pcol = (16 * lt + fr) ^ pswz;
#pragma unroll
        for (int j = 0; j < 4; ++j)
            utT[(16 * w + 4 * hi + j) * LTP + pcol] = (_Float16)acc[j];
        if (lt < 12) {
            half4v h = { (_Float16)xv.x, (_Float16)xv.y, (_Float16)xv.z, (_Float16)xv.w };
            *(half4v*)&nxt[w * CP + sc4] = h;
        }
        __syncthreads();
    }

    // ---------- one-time register gathers (bw dead; zf/au born) ----------
    // zf: lane(fr,hi) reads virtual cols 32ks+8hi.. of row 16w+fr
    const int zswz = ((2 * w + (fr >> 3)) & 3) << 3;
    half8 zf[7];
#pragma unroll
    for (int ks = 0; ks < 7; ++ks)
        zf[ks] = *(const half8*)&utT[(16 * w + fr) * LTP + ((32 * ks + 8 * hi) ^ zswz)];
    // au: wave w<13, rows 32d0+8hi+j -> swz = hi; conflict-free by design
    const int aucol = (16 * w + fr) ^ (hi << 3);
    half8 au[8];
    if (w < 13) {
#pragma unroll
        for (int d0 = 0; d0 < 8; ++d0) {
            _Float16 tmp[8];
#pragma unroll
            for (int j = 0; j < 8; ++j)
                tmp[j] = utT[(32 * d0 + 8 * hi + j) * LTP + aucol];
            au[d0] = *(half8*)tmp;
        }
    }

    // ---------- routing iterations ----------
    for (int iter = 0; iter < 3; ++iter) {
        // A. softmax over l (waves 0..7, wave = capsule k); hi/lo fp16 w
        if (t < 512) {
            const int k = t >> 6, ln = t & 63;
            float v[4];
            float m = -1e30f;
#pragma unroll
            for (int i = 0; i < 4; ++i) {
                const int l = ln + 64 * i;
                v[i] = (l < L_) ? lb[k * L_ + l] : -1e30f;
                m = fmaxf(m, v[i]);
            }
#pragma unroll
            for (int off = 32; off >= 1; off >>= 1)
                m = fmaxf(m, __shfl_xor(m, off));
            float e[4], s = 0.f;
#pragma unroll
            for (int i = 0; i < 4; ++i) {
                const int l = ln + 64 * i;
                e[i] = (l < L_) ? __expf(v[i] - m) : 0.f;
                s += e[i];
            }
#pragma unroll
            for (int off = 32; off >= 1; off >>= 1)
                s += __shfl_xor(s, off);
            const float rinv = 1.0f / s;
#pragma unroll
            for (int i = 0; i < 4; ++i) {
                const int l = ln + 64 * i;
                if (l < L_) {
                    const float wv = e[i] * rinv;
                    const _Float16 h = (_Float16)wv;
                    wHs[k * WP + l] = h;
                    wLs[k * WP + l] = (_Float16)(wv - (float)h);
                }
            }
        }
        __syncthreads();

        // B. z-pass MFMA: A = wH/wL (LDS), B = zf (regs); two chains
        f32x4 zH = {}, zL = {};
#pragma unroll
        for (int ks = 0; ks < 7; ++ks) {
            const half8 ah = *(const half8*)&wHs[fr * WP + 32 * ks + 8 * hi];
            const half8 al = *(const half8*)&wLs[fr * WP + 32 * ks + 8 * hi];
            zH = __builtin_amdgcn_mfma_f32_16x16x32_f16(ah, zf[ks], zH, 0, 0, 0);
            zL = __builtin_amdgcn_mfma_f32_16x16x32_f16(al, zf[ks], zL, 0, 0, 0);
        }
        const float z0 = zH[0] + zL[0], z1 = zH[1] + zL[1];
        const float z2 = zH[2] + zL[2], z3 = zH[3] + zL[3];

        // C. norms: reduce z^2 over fr (16-lane groups)
        float sq0 = z0 * z0, sq1 = z1 * z1, sq2 = z2 * z2, sq3 = z3 * z3;
#pragma unroll
        for (int off = 1; off <= 8; off <<= 1) {
            sq0 += __shfl_xor(sq0, off);
            sq1 += __shfl_xor(sq1, off);
            sq2 += __shfl_xor(sq2, off);
            sq3 += __shfl_xor(sq3, off);
        }
        if (fr == 0 && hi < 2) {
            f32x4 sv = { sq0, sq1, sq2, sq3 };
            *(f32x4*)&red2[w * 8 + 4 * hi] = sv;
        }
        __syncthreads();

        // D. squash scale, redundant per wave + shfl broadcast
        float myscale = 0.f;
        if (lane < 8) {
            float ns = 0.f;
#pragma unroll
            for (int ww = 0; ww < 16; ++ww) ns += red2[ww * 8 + lane];
            myscale = ns / ((1.f + ns) * sqrtf(ns + 1e-8f));
        }
        const float sc0 = __shfl(myscale, 4 * hi + 0);
        const float sc1 = __shfl(myscale, 4 * hi + 1);
        const float sc2 = __shfl(myscale, 4 * hi + 2);
        const float sc3 = __shfl(myscale, 4 * hi + 3);

        // E. emit c (hi/lo fp16) or final output
        if (iter == 2) {
            if (hi < 2) {
                float* op = out + (size_t)b * (K_ * D_) + (4 * hi) * D_ + 16 * w + fr;
                op[0 * D_] = sc0 * z0;
                op[1 * D_] = sc1 * z1;
                op[2 * D_] = sc2 * z2;
                op[3 * D_] = sc3 * z3;
            }
        } else {
            if (hi < 2) {
                const float v0 = sc0 * z0, v1 = sc1 * z1;
                const float v2 = sc2 * z2, v3 = sc3 * z3;
                const _Float16 h0 = (_Float16)v0, h1 = (_Float16)v1;
                const _Float16 h2 = (_Float16)v2, h3 = (_Float16)v3;
                const int cb = 16 * w + fr;
                cHs[(4 * hi + 0) * CP + cb] = h0;
                cHs[(4 * hi + 1) * CP + cb] = h1;
                cHs[(4 * hi + 2) * CP + cb] = h2;
                cHs[(4 * hi + 3) * CP + cb] = h3;
                cLs[(4 * hi + 0) * CP + cb] = (_Float16)(v0 - (float)h0);
                cLs[(4 * hi + 1) * CP + cb] = (_Float16)(v1 - (float)h1);
                cLs[(4 * hi + 2) * CP + cb] = (_Float16)(v2 - (float)h2);
                cLs[(4 * hi + 3) * CP + cb] = (_Float16)(v3 - (float)h3);
            }
            __syncthreads();

            // F. b-update MFMA: A = au regs, B = cH/cL LDS (two chains)
            if (w < 13) {
                f32x4 dH = {}, dL = {};
#pragma unroll
                for (int d0 = 0; d0 < 8; ++d0) {
                    const half8 bh = *(const half8*)&cHs[fr * CP + 32 * d0 + 8 * hi];
                    const half8 bl = *(const half8*)&cLs[fr * CP + 32 * d0 + 8 * hi];
                    dH = __builtin_amdgcn_mfma_f32_16x16x32_f16(au[d0], bh, dH, 0, 0, 0);
                    dL = __builtin_amdgcn_mfma_f32_16x16x32_f16(au[d0], bl, dL, 0, 0, 0);
                }
                if (fr < 8) {
#pragma unroll
                    for (int j = 0; j < 4; ++j) {
                        const int l = 16 * w + 4 * hi + j;
                        if (l < L_) lb[fr * L_ + l] += dH[j] + dL[j];
                    }
                }
            }
            __syncthreads();
        }
    }
}

// ==================================================================
extern "C" void kernel_launch(void* const* d_in, const int* in_sizes, int n_in,
                              void* d_out, int out_size, void* d_ws, size_t ws_size,
                              hipStream_t stream) {
    (void)in_sizes; (void)n_in; (void)out_size; (void)ws_size;
    const float* behavior = (const float*)d_in[0];   // [B, L, D]
    const float* W        = (const float*)d_in[1];   // [D, D]
    const float* b_init   = (const float*)d_in[2];   // [B, K, L]
    const int*   mask     = (const int*)d_in[3];     // [B, L]
    float* out      = (float*)d_out;                 // [B, K, D]
    _Float16* Wh    = (_Float16*)d_ws;               // [256,256] fp16

    hipFuncSetAttribute((const void*)fused_mie7,
                        hipFuncAttributeMaxDynamicSharedMemorySize, LDS_TOTAL);

    w_to_f16<<<64, 256, 0, stream>>>(W, Wh);
    fused_mie7<<<B_, 1024, LDS_TOTAL, stream>>>(behavior, b_init, mask, Wh, out);
}